// Round 9
// baseline (250.622 us; speedup 1.0000x reference)
//
#include <hip/hip_runtime.h>

// P2B_XCorr: B=8, F=128, M=256, N=1024, H=64, O=128. fp32 I/O.
// R9: flash-style fusion — cos computed INSIDE k_main per block (t/s slabs staged
//   f16 in LDS, norms fp32 during staging, QK via MFMA -> cos tile in LDS; k_cos
//   kernel deleted). z=4 m-splits (1024 blocks, 4/CU; LDS phase-overlay 32.9 KB).
//   Main loop unrolled x2 with double-buffered h2 scratch: one lgkmcnt(0) per 2 mc,
//   next-pair cos/A1 prefetch issued before the barrier. L3 bias folded out of the
//   loop (p=max(z) with p init -inf; relu(p+c3) once at store).
// Frag layouts (HW-verified): A[m=lane&15][k=quad*8+j], B[k=quad*8+j][n=lane&15],
// D[row=quad*4+reg][col=lane&15].

#define BB 8
#define FF 128
#define MM 256
#define NN 1024
#define HH 64
#define OO 128
#define BN_EPS 1e-5f
#define COS_EPS 1e-8f

// ws layout (float offsets); ends at 2,175,232 floats = 8.30 MiB (< proven 8.59)
#define WS_U     0
#define WS_C2    64
#define WS_C3    128
#define WS_CC1   192
#define WS_W2F   256
#define WS_W3F   4352
#define WS_WC1F  8448
#define WS_A1    12544        // f16 A1H[b][m][64] -> 65536 floats
#define WS_P     78080        // fp32 partials [4][b][n][64]
#define PS       524288

typedef _Float16 half2v __attribute__((ext_vector_type(2)));
typedef _Float16 half8  __attribute__((ext_vector_type(8)));
typedef __attribute__((ext_vector_type(4))) float f32x4;

__device__ __forceinline__ unsigned int pkh2(float a, float b){
  auto h = __builtin_amdgcn_cvt_pkrtz(a, b);
  return __builtin_bit_cast(unsigned int, h);
}
__device__ __forceinline__ half2v u2h(unsigned int u){
  return __builtin_bit_cast(half2v, u);
}
__device__ __forceinline__ unsigned int h2u(half2v v){
  return __builtin_bit_cast(unsigned int, v);
}
__device__ __forceinline__ unsigned int relu2(unsigned int d){
  half2v v = __builtin_elementwise_max(u2h(d), (half2v){(_Float16)0, (_Float16)0});
  return h2u(v);
}
__device__ __forceinline__ unsigned int bh1(unsigned int up, half2v c, unsigned int ap){
  half2v v = __builtin_elementwise_fma(u2h(up), c, u2h(ap));
  v = __builtin_elementwise_max(v, (half2v){(_Float16)0, (_Float16)0});
  return h2u(v);
}
__device__ __forceinline__ float dot4(float4 a, float4 b, float acc){
  acc = fmaf(a.x, b.x, acc); acc = fmaf(a.y, b.y, acc);
  acc = fmaf(a.z, b.z, acc); acc = fmaf(a.w, b.w, acc);
  return acc;
}

// ---------------- K1: prep (role-split: a1 | fold) ----------------
__global__ __launch_bounds__(256) void k_prep(const float* t_,
    const float* W1, const float* W2, const float* W3, const float* Wc1,
    const float* g1, const float* b1, const float* m1, const float* v1,
    const float* g2, const float* b2, const float* m2, const float* v2,
    const float* g3, const float* b3, const float* m3, const float* v3,
    const float* gc1,const float* bc1,const float* mc1,const float* vc1,
    float* ws){
  __shared__ float W1s[64][133];
  int t = threadIdx.x;
  int bx = blockIdx.x;
  if (bx < 256){
    // ---- A1H[b][m][h] (f16) ----
    int b = bx >> 5, m0 = (bx & 31)*8;
    for (int idx = t; idx < 8192; idx += 256){
      int h = idx >> 7, f = idx & 127;
      W1s[h][f] = W1[h*129 + 1 + f];
    }
    __syncthreads();
    int h = t & 63, mg = t >> 6;
    const float* tp = t_ + (size_t)b*FF*MM + m0 + mg*2;
    float acc0 = 0.f, acc1 = 0.f;
    for (int f = 0; f < FF; f++){
      float wv = W1s[h][f];
      float2 tv = *(const float2*)&tp[(size_t)f*MM];
      acc0 = fmaf(wv, tv.x, acc0); acc1 = fmaf(wv, tv.y, acc1);
    }
    float a1 = g1[h] / sqrtf(v1[h] + BN_EPS);
    float c1 = b1[h] - a1*m1[h];
    unsigned short* dst = (unsigned short*)(ws + WS_A1) + ((size_t)(b*MM + m0 + mg*2))*64 + h;
    dst[0]  = (unsigned short)(pkh2(fmaf(a1, acc0, c1), 0.f) & 0xFFFFu);
    dst[64] = (unsigned short)(pkh2(fmaf(a1, acc1, c1), 0.f) & 0xFFFFu);
  } else {
    // ---- fold ----
    if (t < 64){
      float a1 = g1[t] / sqrtf(v1[t] + BN_EPS);
      ws[WS_U + t]   = a1 * W1[t*129];
      float a2 = g2[t] / sqrtf(v2[t] + BN_EPS);
      ws[WS_C2 + t]  = b2[t] - a2*m2[t];
      float a3 = g3[t] / sqrtf(v3[t] + BN_EPS);
      ws[WS_C3 + t]  = b3[t] - a3*m3[t];
      float ac = gc1[t] / sqrtf(vc1[t] + BN_EPS);
      ws[WS_CC1 + t] = bc1[t] - ac*mc1[t];
    }
    for (int i = t; i < 4096; i += 256){
      int g = i >> 6;
      float a2 = g2[g] / sqrtf(v2[g] + BN_EPS);
      ws[WS_W2F + i]  = a2 * W2[i];
      float a3 = g3[g] / sqrtf(v3[g] + BN_EPS);
      ws[WS_W3F + i]  = a3 * W3[i];
      float ac = gc1[g] / sqrtf(vc1[g] + BN_EPS);
      ws[WS_WC1F + i] = ac * Wc1[i];
    }
  }
}

// ---------------- K2: fused main. grid (32, 8, 4), 4 waves ----------------
// Phase 1: stage t(64m)/s(32n) slabs f16 + fp32 norms; QK MFMA -> cosL (LDS).
// Phase 2: 32-m loop (wave parity), h1 B-frags in regs, L2 MFMA, h2 LDS transpose
// (double-buffered, 1 wait/2mc), L3 MFMA, p = running max (init -inf).
__global__ __launch_bounds__(256, 4) void k_main(const float* t_, const float* s_,
                                                 const float* ws, float* Pp){
  // manual LDS overlay: total 32896 B
  __shared__ __align__(16) char smem[32896];
  unsigned short* cosL = (unsigned short*)smem;              // [64][34] u16
  float* ntF = (float*)(smem + 4352);                        // [64]
  float* nsF = (float*)(smem + 4608);                        // [32]
  unsigned short* tT = (unsigned short*)(smem + 4736);       // [64][136] phase1
  unsigned short* sT = (unsigned short*)(smem + 22144);      // [32][136] phase1
  float* redT = (float*)(smem + 30848);                      // [4][64]  phase1
  float* redS = (float*)(smem + 31872);                      // [8][32]  phase1
  unsigned short* h2base = (unsigned short*)(smem + 4736);   // [4][2][16][72] phase2

  int t = threadIdx.x;
  int lane = t & 63, w = t >> 6;
  int ln15 = lane & 15, quad = lane >> 4;
  int b = blockIdx.y;
  int n0 = blockIdx.x * 32;
  int m0 = blockIdx.z * 64;

  // ---- phase 1a: stage slabs + norm partials ----
  {
    int fg = t >> 6;           // 0..3, f-range fg*32..+31, lane = m
    const float* tb = t_ + ((size_t)(b*FF + fg*32))*MM + m0 + lane;
    float accT = 0.f;
    #pragma unroll
    for (int k = 0; k < 16; k++){
      float va = tb[(size_t)(2*k)*MM], vb = tb[(size_t)(2*k+1)*MM];
      accT = fmaf(va, va, accT); accT = fmaf(vb, vb, accT);
      *(unsigned int*)&tT[lane*136 + fg*32 + 2*k] = pkh2(va, vb);
    }
    redT[fg*64 + lane] = accT;
    int n = t & 31, fg2 = t >> 5;  // 0..7, f-range fg2*16..+15
    const float* sb = s_ + ((size_t)(b*FF + fg2*16))*NN + n0 + n;
    float accS = 0.f;
    #pragma unroll
    for (int k = 0; k < 8; k++){
      float va = sb[(size_t)(2*k)*NN], vb = sb[(size_t)(2*k+1)*NN];
      accS = fmaf(va, va, accS); accS = fmaf(vb, vb, accS);
      *(unsigned int*)&sT[n*136 + fg2*16 + 2*k] = pkh2(va, vb);
    }
    redS[fg2*32 + n] = accS;
  }
  __syncthreads();
  if (t < 64){
    ntF[t] = sqrtf(redT[t] + redT[64+t] + redT[128+t] + redT[192+t]);
  } else if (t < 96){
    int n = t - 64;
    float s = redS[n] + redS[32+n] + redS[64+n] + redS[96+n]
            + redS[128+n] + redS[160+n] + redS[192+n] + redS[224+n];
    nsF[n] = sqrtf(s);
  }
  __syncthreads();
  // ---- phase 1b: QK -> cosL. wave w owns m-band w*16..+15, both 16-n tiles ----
  {
    half8 At[4];
    #pragma unroll
    for (int kc = 0; kc < 4; kc++)
      At[kc] = *(const half8*)&tT[(w*16 + ln15)*136 + kc*32 + quad*8];
    float4 ntv = *(const float4*)&ntF[w*16 + quad*4];
    #pragma unroll
    for (int nt2 = 0; nt2 < 2; nt2++){
      f32x4 acc = (f32x4){0.f,0.f,0.f,0.f};
      #pragma unroll
      for (int kc = 0; kc < 4; kc++){
        half8 Bs = *(const half8*)&sT[(nt2*16 + ln15)*136 + kc*32 + quad*8];
        acc = __builtin_amdgcn_mfma_f32_16x16x32_f16(At[kc], Bs, acc, 0, 0, 0);
      }
      float nsv = nsF[nt2*16 + ln15];
      #pragma unroll
      for (int r = 0; r < 4; r++){
        float denom = fmaxf(ntv[r == 0 ? 0 : (r == 1 ? 1 : (r == 2 ? 2 : 3))] * nsv, COS_EPS);
        float c = acc[r] * __builtin_amdgcn_rcpf(denom);
        cosL[(w*16 + quad*4 + r)*34 + nt2*16 + ln15] = (unsigned short)(pkh2(c, 0.f) & 0xFFFFu);
      }
    }
  }
  __syncthreads();   // cosL done; tT/sT dead -> h2base region now owned by phase 2

  // ---- phase 2 setup ----
  const float* w2p = ws + WS_W2F;
  const float* w3p = ws + WS_W3F;
  half8 W2A[4][2], W3A[4][2];
  f32x4 c2v[4];
  #pragma unroll
  for (int rt = 0; rt < 4; rt++){
    int g = rt*16 + ln15;
    #pragma unroll
    for (int kk = 0; kk < 2; kk++){
      half8 a2, a3;
      #pragma unroll
      for (int j = 0; j < 8; j++){
        int k = kk*32 + quad*8 + j;
        a2[j] = (_Float16)w2p[g*64 + k];
        a3[j] = (_Float16)w3p[g*64 + k];
      }
      W2A[rt][kk] = a2; W3A[rt][kk] = a3;
    }
    float4 cb2 = *(const float4*)&ws[WS_C2 + rt*16 + quad*4];
    c2v[rt] = (f32x4){cb2.x, cb2.y, cb2.z, cb2.w};
  }
  unsigned int upk[2][4];
  #pragma unroll
  for (int kk = 0; kk < 2; kk++){
    float4 ua = *(const float4*)&ws[WS_U + kk*32 + quad*8];
    float4 ub = *(const float4*)&ws[WS_U + kk*32 + quad*8 + 4];
    upk[kk][0] = pkh2(ua.x, ua.y); upk[kk][1] = pkh2(ua.z, ua.w);
    upk[kk][2] = pkh2(ub.x, ub.y); upk[kk][3] = pkh2(ub.z, ub.w);
  }
  const unsigned short* A1H = (const unsigned short*)(ws + WS_A1) + (size_t)b*MM*64;
  int mp = w >> 1;                       // m-parity of this wave
  int nl = (w & 1)*16 + ln15;            // lane's local n
  int n  = n0 + nl;
  unsigned short* h2w = h2base + w*2304; // 2 bufs x 1152 shorts

  f32x4 p[4];
  #pragma unroll
  for (int rt = 0; rt < 4; rt++) p[rt] = (f32x4){-3e38f, -3e38f, -3e38f, -3e38f};
  const f32x4 ZER4 = (f32x4){0.f,0.f,0.f,0.f};

  // A1 preload for pair (0,1)
  uint4 aAa = *(const uint4*)&A1H[(size_t)(m0 + 0*2 + mp)*64 + quad*8];
  uint4 aAb = *(const uint4*)&A1H[(size_t)(m0 + 0*2 + mp)*64 + 32 + quad*8];
  uint4 aBa = *(const uint4*)&A1H[(size_t)(m0 + 1*2 + mp)*64 + quad*8];
  uint4 aBb = *(const uint4*)&A1H[(size_t)(m0 + 1*2 + mp)*64 + 32 + quad*8];
  unsigned int cuA = cosL[(0*2 + mp)*34 + nl];
  unsigned int cuB = cosL[(1*2 + mp)*34 + nl];

  for (int i = 0; i < 32; i += 2){
    // ---- iter i (buf0): build h1 in regs -> L2 -> h2 write ----
    {
      unsigned int cd = cuA | (cuA << 16);
      half2v ch = u2h(cd);
      uint4 q0, q1;
      q0.x = bh1(upk[0][0], ch, aAa.x); q0.y = bh1(upk[0][1], ch, aAa.y);
      q0.z = bh1(upk[0][2], ch, aAa.z); q0.w = bh1(upk[0][3], ch, aAa.w);
      q1.x = bh1(upk[1][0], ch, aAb.x); q1.y = bh1(upk[1][1], ch, aAb.y);
      q1.z = bh1(upk[1][2], ch, aAb.z); q1.w = bh1(upk[1][3], ch, aAb.w);
      half8 b0h = __builtin_bit_cast(half8, q0);
      half8 b1h = __builtin_bit_cast(half8, q1);
      f32x4 acc[4];
      #pragma unroll
      for (int rt = 0; rt < 4; rt++){
        acc[rt] = __builtin_amdgcn_mfma_f32_16x16x32_f16(W2A[rt][0], b0h, c2v[rt], 0, 0, 0);
        acc[rt] = __builtin_amdgcn_mfma_f32_16x16x32_f16(W2A[rt][1], b1h, acc[rt], 0, 0, 0);
      }
      #pragma unroll
      for (int rt = 0; rt < 4; rt++){
        uint2 vv;
        vv.x = relu2(pkh2(acc[rt][0], acc[rt][1]));
        vv.y = relu2(pkh2(acc[rt][2], acc[rt][3]));
        *(uint2*)&h2w[ln15*72 + rt*16 + quad*4] = vv;
      }
    }
    // ---- iter i+1 (buf1) ----
    {
      unsigned int cd = cuB | (cuB << 16);
      half2v ch = u2h(cd);
      uint4 q0, q1;
      q0.x = bh1(upk[0][0], ch, aBa.x); q0.y = bh1(upk[0][1], ch, aBa.y);
      q0.z = bh1(upk[0][2], ch, aBa.z); q0.w = bh1(upk[0][3], ch, aBa.w);
      q1.x = bh1(upk[1][0], ch, aBb.x); q1.y = bh1(upk[1][1], ch, aBb.y);
      q1.z = bh1(upk[1][2], ch, aBb.z); q1.w = bh1(upk[1][3], ch, aBb.w);
      half8 b0h = __builtin_bit_cast(half8, q0);
      half8 b1h = __builtin_bit_cast(half8, q1);
      f32x4 acc[4];
      #pragma unroll
      for (int rt = 0; rt < 4; rt++){
        acc[rt] = __builtin_amdgcn_mfma_f32_16x16x32_f16(W2A[rt][0], b0h, c2v[rt], 0, 0, 0);
        acc[rt] = __builtin_amdgcn_mfma_f32_16x16x32_f16(W2A[rt][1], b1h, acc[rt], 0, 0, 0);
      }
      #pragma unroll
      for (int rt = 0; rt < 4; rt++){
        uint2 vv;
        vv.x = relu2(pkh2(acc[rt][0], acc[rt][1]));
        vv.y = relu2(pkh2(acc[rt][2], acc[rt][3]));
        *(uint2*)&h2w[1152 + ln15*72 + rt*16 + quad*4] = vv;
      }
    }
    // ---- prefetch next pair (cos drained by barrier; A1 rides vmcnt) ----
    int i2 = (i + 2 < 32) ? i + 2 : 30;
    int i3 = (i + 3 < 32) ? i + 3 : 31;
    unsigned int cuA2 = cosL[(i2*2 + mp)*34 + nl];
    unsigned int cuB2 = cosL[(i3*2 + mp)*34 + nl];
    uint4 nAa = *(const uint4*)&A1H[(size_t)(m0 + i2*2 + mp)*64 + quad*8];
    uint4 nAb = *(const uint4*)&A1H[(size_t)(m0 + i2*2 + mp)*64 + 32 + quad*8];
    uint4 nBa = *(const uint4*)&A1H[(size_t)(m0 + i3*2 + mp)*64 + quad*8];
    uint4 nBb = *(const uint4*)&A1H[(size_t)(m0 + i3*2 + mp)*64 + 32 + quad*8];
    __asm__ volatile("s_waitcnt lgkmcnt(0)" ::: "memory");
    // ---- transposed reads -> L3 -> running max, both bufs ----
    {
      half8 e0 = *(const half8*)&h2w[ln15*72 + quad*8];
      half8 e1 = *(const half8*)&h2w[ln15*72 + 32 + quad*8];
      #pragma unroll
      for (int rt = 0; rt < 4; rt++){
        f32x4 a3 = __builtin_amdgcn_mfma_f32_16x16x32_f16(W3A[rt][0], e0, ZER4, 0, 0, 0);
        a3 = __builtin_amdgcn_mfma_f32_16x16x32_f16(W3A[rt][1], e1, a3, 0, 0, 0);
        #pragma unroll
        for (int r = 0; r < 4; r++) p[rt][r] = fmaxf(p[rt][r], a3[r]);
      }
      half8 f0 = *(const half8*)&h2w[1152 + ln15*72 + quad*8];
      half8 f1 = *(const half8*)&h2w[1152 + ln15*72 + 32 + quad*8];
      #pragma unroll
      for (int rt = 0; rt < 4; rt++){
        f32x4 a3 = __builtin_amdgcn_mfma_f32_16x16x32_f16(W3A[rt][0], f0, ZER4, 0, 0, 0);
        a3 = __builtin_amdgcn_mfma_f32_16x16x32_f16(W3A[rt][1], f1, a3, 0, 0, 0);
        #pragma unroll
        for (int r = 0; r < 4; r++) p[rt][r] = fmaxf(p[rt][r], a3[r]);
      }
    }
    cuA = cuA2; cuB = cuB2;
    aAa = nAa; aAb = nAb; aBa = nBa; aBb = nBb;
  }

  // ---- cross-parity combine + bias/relu + store partial ----
  __syncthreads();
  float* redBuf = (float*)(smem + 4736);   // 32 x 66 floats
  if (w >= 2){
    #pragma unroll
    for (int rt = 0; rt < 4; rt++){
      f32x4 v = p[rt];
      *(float4*)&redBuf[(size_t)((nl)*66 + rt*16 + quad*4)] =
          make_float4(v[0], v[1], v[2], v[3]);
    }
  }
  __syncthreads();
  if (w < 2){
    float* Pb = Pp + (size_t)blockIdx.z*PS + ((size_t)(b*NN + n) << 6);
    #pragma unroll
    for (int rt = 0; rt < 4; rt++){
      float4 o = *(const float4*)&redBuf[(size_t)((nl)*66 + rt*16 + quad*4)];
      float4 c3r = *(const float4*)&ws[WS_C3 + rt*16 + quad*4];
      float4 r4;
      r4.x = fmaxf(fmaxf(p[rt][0], o.x) + c3r.x, 0.f);
      r4.y = fmaxf(fmaxf(p[rt][1], o.y) + c3r.y, 0.f);
      r4.z = fmaxf(fmaxf(p[rt][2], o.z) + c3r.z, 0.f);
      r4.w = fmaxf(fmaxf(p[rt][3], o.w) + c3r.w, 0.f);
      *(float4*)&Pb[rt*16 + quad*4] = r4;
    }
  }
}

// ---------------- K3: tail (max 4 partials, Wc1f/relu, Wc2+bias) fp32 ----------------
__global__ __launch_bounds__(256) void k_tail(const float* Wc2, const float* bc2,
                                              const float* ws, float* out){
  __shared__ float WT[64][68];
  __shared__ float pT[32][68];
  __shared__ float cS[32][68];
  int t = threadIdx.x;
  int n0 = blockIdx.x * 32;
  int b = blockIdx.y;
  for (int i = t; i < 4096; i += 256) WT[i >> 6][i & 63] = ws[WS_WC1F + i];
  const float* P0 = ws + WS_P + ((size_t)(b*NN + n0) << 6);
  for (int i = t; i < 2048; i += 256){
    float v = fmaxf(fmaxf(P0[i], P0[PS + i]), fmaxf(P0[2*PS + i], P0[3*PS + i]));
    pT[i >> 6][i & 63] = v;
  }
  __syncthreads();
  {
    int n = t & 31, q = t >> 5;
    for (int k = 0; k < 8; k++){
      int g = q*8 + k;
      float acc = ws[WS_CC1 + g];
      for (int hs = 0; hs < 64; hs += 4){
        float4 wv = *(const float4*)&WT[g][hs];
        float4 pv = *(const float4*)&pT[n][hs];
        acc = dot4(wv, pv, acc);
      }
      cS[n][g] = fmaxf(acc, 0.f);
    }
  }
  __syncthreads();
  {
    int o = t & 127, hf = t >> 7;
    float bco = bc2[o];
    float accO[16];
    #pragma unroll
    for (int i = 0; i < 16; i++) accO[i] = bco;
    for (int hs = 0; hs < 64; hs += 4){
      float4 w4 = *(const float4*)&Wc2[o*64 + hs];
      #pragma unroll
      for (int i = 0; i < 16; i++){
        float4 cv = *(const float4*)&cS[hf*16 + i][hs];
        accO[i] = dot4(w4, cv, accO[i]);
      }
    }
    #pragma unroll
    for (int i = 0; i < 16; i++)
      out[((size_t)(b*OO + o))*NN + n0 + hf*16 + i] = accO[i];
  }
}

extern "C" void kernel_launch(void* const* d_in, const int* in_sizes, int n_in,
                              void* d_out, int out_size, void* d_ws, size_t ws_size,
                              hipStream_t stream){
  (void)in_sizes; (void)n_in; (void)out_size; (void)ws_size;
  const float* t_  = (const float*)d_in[0];
  const float* s_  = (const float*)d_in[1];
  const float* W1  = (const float*)d_in[2];
  const float* W2  = (const float*)d_in[3];
  const float* W3  = (const float*)d_in[4];
  const float* Wc1 = (const float*)d_in[5];
  const float* Wc2 = (const float*)d_in[6];
  const float* bc2 = (const float*)d_in[7];
  const float* g1 = (const float*)d_in[8],  *b1 = (const float*)d_in[9],
             * m1 = (const float*)d_in[10], *v1 = (const float*)d_in[11];
  const float* g2 = (const float*)d_in[12], *b2 = (const float*)d_in[13],
             * m2 = (const float*)d_in[14], *v2 = (const float*)d_in[15];
  const float* g3 = (const float*)d_in[16], *b3 = (const float*)d_in[17],
             * m3 = (const float*)d_in[18], *v3 = (const float*)d_in[19];
  const float* gc1 = (const float*)d_in[20], *bc1 = (const float*)d_in[21],
             * mc1 = (const float*)d_in[22], *vc1 = (const float*)d_in[23];
  float* ws = (float*)d_ws;
  float* out = (float*)d_out;

  k_prep<<<257, 256, 0, stream>>>(t_, W1, W2, W3, Wc1,
      g1,b1,m1,v1, g2,b2,m2,v2, g3,b3,m3,v3, gc1,bc1,mc1,vc1, ws);
  k_main<<<dim3(32, 8, 4), 256, 0, stream>>>(t_, s_, ws, ws + WS_P);
  k_tail<<<dim3(32, 8), 256, 0, stream>>>(Wc2, bc2, ws, out);
}